// Round 1
// baseline (374.426 us; speedup 1.0000x reference)
//
#include <hip/hip_runtime.h>

// RLGate fused kernel for MI355X (gfx950).
// Shapes (fixed by setup_inputs): B=4, T=2048, D=1024, E=8, K=2, all fp32.
// d_in order: x[B,T,D], expert_outputs[E,B,T,D], rewards[B,T], W[D,E], b[E],
//             baseline_value[1], noise_u[B,T,E], top_k[1].
// d_out: final_output[B,T,D] ++ aux_loss[1]  (fp32, concatenated flat).
//
// Design: one block (256 threads) per token.
//  - gate GEMV: each thread FMAs a float4 of x against W (L1/L2 resident),
//    8 per-expert partials -> wave shuffle reduce -> LDS cross-wave reduce.
//  - thread 0: softmax (max-subtract), log(p+1e-9), Gumbel top-2
//    (ties -> lowest index, matching jax.lax.top_k; the two consumers are
//    symmetric in the pair so selection ORDER never matters).
//  - all threads: gather 2 expert rows (contiguous 4KB each), average, store.
//  - per-token (reward - baseline)*sum(sel log p) -> d_ws; a second 1-block
//    kernel reduces to aux = -mean. No atomics, no memset dependencies.

#define GATE_EPS 1e-9f

__global__ __launch_bounds__(256) void rlgate_fused(
    const float* __restrict__ x,        // [BT, D]
    const float* __restrict__ eo,       // [E, BT, D]
    const float* __restrict__ rewards,  // [BT]
    const float* __restrict__ W,        // [D, E]
    const float* __restrict__ bvec,     // [E]
    const float* __restrict__ baseline, // [1]
    const float* __restrict__ noise,    // [BT, E]
    float* __restrict__ out,            // [BT, D]
    float* __restrict__ aux_ws,         // [BT]
    int BT, int D)
{
    constexpr int E = 8;
    const int bt   = blockIdx.x;
    const int tid  = threadIdx.x;
    const int lane = tid & 63;
    const int wave = tid >> 6;

    // ---- gate logits: dot(x[bt,:], W[:,e]) for e in [0,8) ----
    const float4 xv = ((const float4*)(x + (size_t)bt * D))[tid];
    const float xs[4] = {xv.x, xv.y, xv.z, xv.w};
    float part[E];
#pragma unroll
    for (int e = 0; e < E; ++e) part[e] = 0.0f;
    const float* wr = W + (size_t)(tid * 4) * E;
#pragma unroll
    for (int j = 0; j < 4; ++j) {
#pragma unroll
        for (int e = 0; e < E; ++e)
            part[e] = fmaf(xs[j], wr[j * E + e], part[e]);
    }
    // wave-64 butterfly reduce for all 8 partials
#pragma unroll
    for (int off = 32; off > 0; off >>= 1) {
#pragma unroll
        for (int e = 0; e < E; ++e)
            part[e] += __shfl_xor(part[e], off, 64);
    }

    __shared__ float red[4][E];
    __shared__ int   sh_idx[2];
    if (lane == 0) {
#pragma unroll
        for (int e = 0; e < E; ++e) red[wave][e] = part[e];
    }
    __syncthreads();

    if (tid == 0) {
        // constants pre-rounded exactly as f32(double expr), matching JAX
        const float c_scale = (float)(1.0 - 2e-7);  // 1 - 2e-7
        const float c_shift = (float)(1e-7);

        float lg[E], lp[E], sc[E];
        float m = -INFINITY;
#pragma unroll
        for (int e = 0; e < E; ++e) {
            lg[e] = red[0][e] + red[1][e] + red[2][e] + red[3][e] + bvec[e];
            m = fmaxf(m, lg[e]);
        }
        float s = 0.0f;
        float ex[E];
#pragma unroll
        for (int e = 0; e < E; ++e) { ex[e] = expf(lg[e] - m); s += ex[e]; }
#pragma unroll
        for (int e = 0; e < E; ++e) {
            float p = ex[e] / s;                       // jax.nn.softmax
            lp[e]   = logf(p + GATE_EPS);              // log(probs + EPS)
            float u = noise[(size_t)bt * E + e] * c_scale + c_shift;
            float g = -logf(-logf(u));                 // Gumbel
            sc[e]   = lp[e] + g;
        }
        // top-2, ties broken by lowest index (strict > keeps first max)
        int i1 = 0; float s1 = sc[0];
#pragma unroll
        for (int e = 1; e < E; ++e) if (sc[e] > s1) { s1 = sc[e]; i1 = e; }
        int i2 = -1; float s2 = -INFINITY;
#pragma unroll
        for (int e = 0; e < E; ++e)
            if (e != i1 && sc[e] > s2) { s2 = sc[e]; i2 = e; }

        sh_idx[0] = i1;
        sh_idx[1] = i2;
        aux_ws[bt] = (rewards[bt] - baseline[0]) * (lp[i1] + lp[i2]);
    }
    __syncthreads();

    // ---- combine: average the two selected expert rows ----
    const size_t b1 = ((size_t)sh_idx[0] * BT + bt) * (size_t)D;
    const size_t b2 = ((size_t)sh_idx[1] * BT + bt) * (size_t)D;
    const float4 a = ((const float4*)(eo + b1))[tid];
    const float4 c = ((const float4*)(eo + b2))[tid];
    float4 o;
    o.x = (a.x + c.x) * 0.5f;
    o.y = (a.y + c.y) * 0.5f;
    o.z = (a.z + c.z) * 0.5f;
    o.w = (a.w + c.w) * 0.5f;
    ((float4*)(out + (size_t)bt * D))[tid] = o;
}

__global__ __launch_bounds__(256) void rlgate_aux_reduce(
    const float* __restrict__ aux_ws, float* __restrict__ out_aux, int BT)
{
    const int tid  = threadIdx.x;
    const int lane = tid & 63;
    const int wave = tid >> 6;
    float s = 0.0f;
    for (int i = tid; i < BT; i += 256) s += aux_ws[i];
#pragma unroll
    for (int off = 32; off > 0; off >>= 1) s += __shfl_xor(s, off, 64);
    __shared__ float red[4];
    if (lane == 0) red[wave] = s;
    __syncthreads();
    if (tid == 0)
        out_aux[0] = -(red[0] + red[1] + red[2] + red[3]) / (float)BT;
}

extern "C" void kernel_launch(void* const* d_in, const int* in_sizes, int n_in,
                              void* d_out, int out_size, void* d_ws, size_t ws_size,
                              hipStream_t stream)
{
    const float* x        = (const float*)d_in[0];
    const float* eo       = (const float*)d_in[1];
    const float* rewards  = (const float*)d_in[2];
    const float* W        = (const float*)d_in[3];
    const float* bvec     = (const float*)d_in[4];
    const float* baseline = (const float*)d_in[5];
    const float* noise    = (const float*)d_in[6];
    // d_in[7] = top_k (always 2 for this problem; top-2 logic hardcoded)

    const int BT = in_sizes[2];              // B*T = 8192
    const int D  = in_sizes[0] / BT;         // 1024

    float* out    = (float*)d_out;           // [BT*D] final_output
    float* outaux = out + (size_t)BT * D;    // [1] aux_loss
    float* aux_ws = (float*)d_ws;            // [BT] scratch

    rlgate_fused<<<BT, D / 4, 0, stream>>>(x, eo, rewards, W, bvec, baseline,
                                           noise, out, aux_ws, BT, D);
    rlgate_aux_reduce<<<1, 256, 0, stream>>>(aux_ws, outaux, BT);
}